// Round 15
// baseline (134.848 us; speedup 1.0000x reference)
//
#include <hip/hip_runtime.h>
#include <hip/hip_bf16.h>

typedef unsigned short u16;
typedef __bf16 bf16x8 __attribute__((ext_vector_type(8)));
typedef float f32x4 __attribute__((ext_vector_type(4)));
typedef unsigned short u16x8 __attribute__((ext_vector_type(8)));
typedef unsigned short u16x4 __attribute__((ext_vector_type(4)));

__device__ __forceinline__ float bf2f(u16 u) {
  unsigned int x = ((unsigned int)u) << 16;
  return __builtin_bit_cast(float, x);
}
__device__ __forceinline__ u16 f2bf(float f) {
  unsigned int x = __builtin_bit_cast(unsigned int, f);
  x = x + 0x7FFFu + ((x >> 16) & 1u);
  return (u16)(x >> 16);
}

// async global->LDS, 16B per lane; LDS dest is wave-uniform base + lane*16.
__device__ __forceinline__ void gload_lds16(const u16* g, u16* l) {
  __builtin_amdgcn_global_load_lds(
      (const __attribute__((address_space(1))) unsigned int*)(unsigned long long)(uintptr_t)g,
      (__attribute__((address_space(3))) unsigned int*)(unsigned int)(uintptr_t)l,
      16, 0, 0);
}

// ---------------- prep (r15) ----------------
// id<4096: cast X. 4096..4607: cast Wq*(1/32) ROW-major -> Wqr.
// 4608..5119: cast Wk ROW-major -> Wkr. 5120..5375: transpose Wv -> WG+1M.
// r14 bug: G was computed from TRANSPOSED W buffers, giving Wk^T*Wq instead
// of M = Wq*Wk^T. The k-contiguous operands for M are the ROW-major weights.
__global__ __launch_bounds__(256) void prep_kernel(const float* __restrict__ X,
                                                   const float* __restrict__ Wq,
                                                   const float* __restrict__ Wk,
                                                   const float* __restrict__ Wv,
                                                   u16* __restrict__ Xb,
                                                   u16* __restrict__ Wqr,
                                                   u16* __restrict__ Wkr,
                                                   u16* __restrict__ WG) {
  const int id = blockIdx.x;
  const int tid = threadIdx.x;
  if (id < 5120) {
    const float* src;
    u16* dst;
    float scale = 1.0f;
    long i;
    if (id < 4096) {
      src = X; dst = Xb; i = ((long)id * 256 + tid) * 8;
    } else if (id < 4608) {
      src = Wq; dst = Wqr; scale = 1.0f / 32.0f;   // fold 1/sqrt(1024)
      i = ((long)(id - 4096) * 256 + tid) * 8;
    } else {
      src = Wk; dst = Wkr;
      i = ((long)(id - 4608) * 256 + tid) * 8;
    }
    float4 a = *reinterpret_cast<const float4*>(src + i);
    float4 b = *reinterpret_cast<const float4*>(src + i + 4);
    u16x8 o;
    o[0] = f2bf(a.x * scale); o[1] = f2bf(a.y * scale);
    o[2] = f2bf(a.z * scale); o[3] = f2bf(a.w * scale);
    o[4] = f2bf(b.x * scale); o[5] = f2bf(b.y * scale);
    o[6] = f2bf(b.z * scale); o[7] = f2bf(b.w * scale);
    *reinterpret_cast<u16x8*>(dst + i) = o;
    return;
  }
  // Wv transpose: WG[1M + c*1024 + r] = Wv[r][c]
  __shared__ u16 t[64][72];
  const int id2 = id - 5120;
  u16* out = WG + 1048576;
  const int c0 = (id2 & 15) * 64;
  const int r0 = (id2 >> 4) * 64;
#pragma unroll
  for (int i = 0; i < 4; ++i) {
    int slot = tid + 256 * i;
    int lr = slot >> 4;
    int lc4 = slot & 15;
    float4 v = *reinterpret_cast<const float4*>(Wv + (long)(r0 + lr) * 1024 + c0 + lc4 * 4);
    t[lr][lc4 * 4 + 0] = f2bf(v.x);
    t[lr][lc4 * 4 + 1] = f2bf(v.y);
    t[lr][lc4 * 4 + 2] = f2bf(v.z);
    t[lr][lc4 * 4 + 3] = f2bf(v.w);
  }
  __syncthreads();
#pragma unroll
  for (int i = 0; i < 2; ++i) {
    int slot = tid + 256 * i;
    int orow = slot >> 3;
    int oc = slot & 7;
    u16x8 o;
#pragma unroll
    for (int j = 0; j < 8; ++j) o[j] = t[oc * 8 + j][orow];
    *reinterpret_cast<u16x8*>(out + (long)(c0 + orow) * 1024 + r0 + oc * 8) = o;
  }
}

// ---------------- 128x128 NT GEMM, 4 waves of 64x64 (r8-proven structure) ----------
// K-PROJECTION ELIMINATED: S = X*M*X^T, M = Wq Wk^T/32.
// MODE 0 (G): Gt = NT(Wkr, Wqr) -> WG[d'][d] = Sum_e Wk[d',e]Wq[d,e]/32
//   = M[d,d']. grid 64. (row-major inputs — the r14 fix.)
// MODE 1 (T1V): A=Xb, B=[Gt;Wvt] (2048 rows). bn<8 -> T1[t][d'] = X*M
//   (swapped epilogue); bn>=8 -> V, normal order, transposed to Vt[b][e][t].
//   grid 1024 = exactly 2.0 rounds at 2 blocks/CU.
// Loop: BK=64, dbuf LDS, one __syncthreads per K-step, stage-after-barrier,
// gload_lds w16, pre-swizzled source + XOR-swizzled ds_read (conflicts = 0).
template <int MODE>
__global__ __launch_bounds__(256, 2) void gemm128(const u16* __restrict__ A,
                                                  const u16* __restrict__ B,
                                                  u16* __restrict__ C,
                                                  u16* __restrict__ Vt) {
  int bm, bn;
  if constexpr (MODE == 0) {
    bm = blockIdx.x >> 3;               // 0..7
    bn = blockIdx.x & 7;
  } else {
    const int id = blockIdx.x;          // 0..1023
    const int xcd = id & 7, j = id >> 3;
    bn = (xcd & 1) * 8 + (j & 7);       // 0..15
    bm = ((xcd >> 1) << 4) + (j >> 3);  // 0..63
  }
  const int m0 = bm * 128, n0 = bn * 128;
  const int K = 1024;

  bool vblk = false;
  if constexpr (MODE == 1) vblk = (bn >> 3) == 1;

  __shared__ u16 ldsA[2][8192];
  __shared__ u16 ldsB[2][8192];

  const int tid = threadIdx.x;
  const int lane = tid & 63;
  const int wid = tid >> 6;
  const int wm = wid >> 1, wn = wid & 1;
  const int l16 = lane & 15, lh = lane >> 4;
  const int srow = lane >> 3;
  const int scol = ((lane & 7) ^ srow) * 8;  // pre-swizzled source column
  const int rsw = l16 & 7;                   // read-side swizzle key

  f32x4 acc[4][4];
#pragma unroll
  for (int mi = 0; mi < 4; ++mi)
#pragma unroll
    for (int ni = 0; ni < 4; ++ni) acc[mi][ni] = (f32x4)(0.0f);

  auto stage = [&](int d, int k0) {
#pragma unroll
    for (int s = 0; s < 4; ++s) {
      const int seg = wid * 4 + s;           // 0..15 (1KB segments)
      const int row = seg * 8 + srow;        // 0..127
      gload_lds16(A + (long)(m0 + row) * K + k0 + scol, &ldsA[d][seg * 512]);
      gload_lds16(B + (long)(n0 + row) * K + k0 + scol, &ldsB[d][seg * 512]);
    }
  };

  stage(0, 0);
  int cur = 0;
  for (int k0 = 0; k0 < K; k0 += 64) {
    __syncthreads();                          // buf[cur] ready; old readers done
    if (k0 + 64 < K) stage(cur ^ 1, k0 + 64); // lands during compute below
#pragma unroll
    for (int kk = 0; kk < 2; ++kk) {
      bf16x8 af[4], bfr[4];
#pragma unroll
      for (int mi = 0; mi < 4; ++mi)
        af[mi] = *reinterpret_cast<const bf16x8*>(
            &ldsA[cur][(wm * 64 + mi * 16 + l16) * 64 + (((kk * 4 + lh) ^ rsw)) * 8]);
#pragma unroll
      for (int ni = 0; ni < 4; ++ni)
        bfr[ni] = *reinterpret_cast<const bf16x8*>(
            &ldsB[cur][(wn * 64 + ni * 16 + l16) * 64 + (((kk * 4 + lh) ^ rsw)) * 8]);
      if (!vblk) {
#pragma unroll
        for (int mi = 0; mi < 4; ++mi)
#pragma unroll
          for (int ni = 0; ni < 4; ++ni)
            acc[mi][ni] = __builtin_amdgcn_mfma_f32_16x16x32_bf16(bfr[ni], af[mi], acc[mi][ni], 0, 0, 0);
      } else {
#pragma unroll
        for (int mi = 0; mi < 4; ++mi)
#pragma unroll
          for (int ni = 0; ni < 4; ++ni)
            acc[mi][ni] = __builtin_amdgcn_mfma_f32_16x16x32_bf16(af[mi], bfr[ni], acc[mi][ni], 0, 0, 0);
      }
    }
    cur ^= 1;
  }

  if (!vblk) {
    // Swapped: C[m0+wm*64+mi*16+l16][col0+wn*64+ni*16+lh*4+r] = acc[mi][ni][r]
    const int col0 = (MODE == 0) ? n0 : (bn & 7) * 128;
    const long rown = (long)(m0 + wm * 64 + l16);
    const int coln = col0 + wn * 64 + lh * 4;
#pragma unroll
    for (int mi = 0; mi < 4; ++mi)
#pragma unroll
      for (int ni = 0; ni < 4; ++ni) {
        u16x4 o;
#pragma unroll
        for (int r = 0; r < 4; ++r) o[r] = f2bf(acc[mi][ni][r]);
        *reinterpret_cast<u16x4*>(&C[(rown + mi * 16) * 1024 + coln + ni * 16]) = o;
      }
  } else {
    // V (normal order): D row = M-dim(t). Vt[b][e][t], vector along t.
    const int b = m0 >> 11;
    const int t0 = (m0 & 2047) + wm * 64 + lh * 4;
    const int e0 = (bn & 7) * 128 + wn * 64 + l16;
#pragma unroll
    for (int mi = 0; mi < 4; ++mi)
#pragma unroll
      for (int ni = 0; ni < 4; ++ni) {
        u16x4 o;
#pragma unroll
        for (int r = 0; r < 4; ++r) o[r] = f2bf(acc[mi][ni][r]);
        *reinterpret_cast<u16x4*>(
            &Vt[(long)b * 2097152 + (long)(e0 + ni * 16) * 2048 + t0 + mi * 16]) = o;
      }
  }
}

// ---------------- S = exp(T1 X^T): 64x128 tiles, BK=64, 3/CU (r13, unchanged) -----
__global__ __launch_bounds__(256, 3) void gemm_s(const u16* __restrict__ T1,
                                                 const u16* __restrict__ Xb,
                                                 u16* __restrict__ Sg,
                                                 float* __restrict__ Sums) {
  const int id = blockIdx.x;            // 0..1087
  const int x = id & 7;                 // XCD (round-robin assumption)
  const int q = id >> 3;                // 0..135
  const int bz = q / 34;
  int u = q - bz * 34;
  int qr, kc;
  const int n1 = 32 - 2 * x;            // tiles with kc = x  (qr = 2x..31)
  if (u < n1) { kc = x;      qr = 2 * x + u; }
  else        { kc = 15 - x; qr = 30 - 2 * x + (u - n1); }
  const int m0 = qr * 64, n0 = kc * 128;
  const int K = 1024;

  const u16* A = T1 + (long)bz * 2097152;
  const u16* B = Xb + (long)bz * 2097152;

  __shared__ u16 ldsA[2][4096];    // 64 x 64
  __shared__ u16 ldsB[2][8192];    // 128 x 64

  const int tid = threadIdx.x;          // 0..255
  const int lane = tid & 63;
  const int wn = tid >> 6;              // wave 0..3 owns cols wn*32..wn*32+31
  const int l16 = lane & 15, lh = lane >> 4;
  const int strow = tid >> 3;                       // 0..31
  const int scol = ((tid & 7) ^ (strow & 7)) * 8;   // pre-swizzled source col
  const int rsw = l16 & 7;                          // read-side swizzle key

  f32x4 acc[4][2];
#pragma unroll
  for (int mi = 0; mi < 4; ++mi)
#pragma unroll
    for (int ni = 0; ni < 2; ++ni) acc[mi][ni] = (f32x4)(0.0f);

  auto stage = [&](int d, int k0) {
#pragma unroll
    for (int l = 0; l < 2; ++l)
      gload_lds16(A + (long)(m0 + l * 32 + strow) * K + k0 + scol,
                  &ldsA[d][l * 2048 + tid * 8]);
#pragma unroll
    for (int l = 0; l < 4; ++l)
      gload_lds16(B + (long)(n0 + l * 32 + strow) * K + k0 + scol,
                  &ldsB[d][l * 2048 + tid * 8]);
  };

  stage(0, 0);
  int cur = 0;
  for (int k0 = 0; k0 < K; k0 += 64) {
    __syncthreads();
    if (k0 + 64 < K) stage(cur ^ 1, k0 + 64);
#pragma unroll
    for (int kk = 0; kk < 2; ++kk) {
      bf16x8 af[4], bfr[2];
#pragma unroll
      for (int mi = 0; mi < 4; ++mi)
        af[mi] = *reinterpret_cast<const bf16x8*>(
            &ldsA[cur][(mi * 16 + l16) * 64 + (((kk * 4 + lh) ^ rsw)) * 8]);
#pragma unroll
      for (int ni = 0; ni < 2; ++ni)
        bfr[ni] = *reinterpret_cast<const bf16x8*>(
            &ldsB[cur][(wn * 32 + ni * 16 + l16) * 64 + (((kk * 4 + lh) ^ rsw)) * 8]);
#pragma unroll
      for (int mi = 0; mi < 4; ++mi)
#pragma unroll
        for (int ni = 0; ni < 2; ++ni)
          acc[mi][ni] = __builtin_amdgcn_mfma_f32_16x16x32_bf16(bfr[ni], af[mi], acc[mi][ni], 0, 0, 0);
    }
    cur ^= 1;
  }

  // P = exp(S), zero above diagonal; row sums from bf16-rounded values.
  u16* C = Sg + (long)bz * 4194304;
  float* sums = Sums + (long)bz * 2048;
  const int coln = n0 + wn * 32 + lh * 4;
#pragma unroll
  for (int mi = 0; mi < 4; ++mi) {
    const int gr = m0 + mi * 16 + l16;
    float rs = 0.0f;
#pragma unroll
    for (int ni = 0; ni < 2; ++ni) {
      u16x4 o;
#pragma unroll
      for (int r = 0; r < 4; ++r) {
        const int gc = coln + ni * 16 + r;
        const float e = (gc <= gr) ? __expf(acc[mi][ni][r]) : 0.0f;
        const u16 ub = f2bf(e);
        o[r] = ub;
        rs += bf2f(ub);
      }
      *reinterpret_cast<u16x4*>(&C[(long)gr * 2048 + coln + ni * 16]) = o;
    }
    rs += __shfl_xor(rs, 16);
    rs += __shfl_xor(rs, 32);
    if (lh == 0) atomicAdd(&sums[gr], rs);
  }
}

// ---------------- PV GEMM: 128x128, 8 waves, balanced pairing (r13, unchanged) ----
__global__ __launch_bounds__(512, 2) void gemm_pv(const u16* __restrict__ Ag,
                                                  const u16* __restrict__ Bg,
                                                  float* __restrict__ Cg,
                                                  const float* __restrict__ Sums) {
  const int id = blockIdx.x;            // 0..511
  const int x = id & 7;                 // XCD; also bn
  const int q = id >> 3;                // 0..63
  const int f = (q ^ (q >> 5)) & 1;
  const int i5 = ((q >> 1) & 15) | (((q >> 5) & 1) << 4);
  const int bmb = i5 & 7;
  const int bz = (i5 >> 3) & 3;
  const int bm = f ? (15 - bmb) : bmb;
  const int bn = x;
  const int K = 2048;

  const u16* A = Ag + (long)bz * 4194304;
  const u16* B = Bg + (long)bz * 2097152;
  const int m0 = bm * 128, n0 = bn * 128;
  const int kEnd = m0 + 128;

  __shared__ u16 ldsA[2][8192];
  __shared__ u16 ldsB[2][8192];

  const int tid = threadIdx.x;          // 0..511
  const int lane = tid & 63;
  const int wid = tid >> 6;             // 0..7
  const int wm = wid >> 2, wn = wid & 3;
  const int l16 = lane & 15, lh = lane >> 4;
  const int strow = tid >> 3;                       // 0..63
  const int scol = ((tid & 7) ^ (strow & 7)) * 8;   // pre-swizzled source column
  const int rsw = l16 & 7;                          // read-side swizzle key

  f32x4 acc[4][2];
#pragma unroll
  for (int mi = 0; mi < 4; ++mi)
#pragma unroll
    for (int ni = 0; ni < 2; ++ni) acc[mi][ni] = (f32x4)(0.0f);

  auto stage = [&](int d, int k0) {
#pragma unroll
    for (int l = 0; l < 2; ++l) {
      const int row = l * 64 + strow;   // 0..127
      gload_lds16(A + (long)(m0 + row) * K + k0 + scol, &ldsA[d][l * 4096 + tid * 8]);
      gload_lds16(B + (long)(n0 + row) * K + k0 + scol, &ldsB[d][l * 4096 + tid * 8]);
    }
  };

  stage(0, 0);
  int cur = 0;
  for (int k0 = 0; k0 < kEnd; k0 += 64) {
    __syncthreads();
    if (k0 + 64 < kEnd) stage(cur ^ 1, k0 + 64);
#pragma unroll
    for (int kk = 0; kk < 2; ++kk) {
      bf16x8 af[4], bfr[2];
#pragma unroll
      for (int mi = 0; mi < 4; ++mi)
        af[mi] = *reinterpret_cast<const bf16x8*>(
            &ldsA[cur][(wm * 64 + mi * 16 + l16) * 64 + (((kk * 4 + lh) ^ rsw)) * 8]);
#pragma unroll
      for (int ni = 0; ni < 2; ++ni)
        bfr[ni] = *reinterpret_cast<const bf16x8*>(
            &ldsB[cur][(wn * 32 + ni * 16 + l16) * 64 + (((kk * 4 + lh) ^ rsw)) * 8]);
#pragma unroll
      for (int mi = 0; mi < 4; ++mi)
#pragma unroll
        for (int ni = 0; ni < 2; ++ni)
          acc[mi][ni] = __builtin_amdgcn_mfma_f32_16x16x32_bf16(bfr[ni], af[mi], acc[mi][ni], 0, 0, 0);
    }
    cur ^= 1;
  }

  // O = acc / rowsum
  float* C = Cg + (long)bz * 2097152;
  const float* sums = Sums + (long)bz * 2048;
  const long rown = (long)(m0 + wm * 64 + l16);
  const int coln = n0 + wn * 32 + lh * 4;
#pragma unroll
  for (int mi = 0; mi < 4; ++mi) {
    const float inv = 1.0f / sums[(int)rown + mi * 16];
#pragma unroll
    for (int ni = 0; ni < 2; ++ni) {
      f32x4 v = acc[mi][ni] * inv;
      *reinterpret_cast<f32x4*>(&C[(rown + mi * 16) * 1024 + coln + ni * 16]) = v;
    }
  }
}

extern "C" void kernel_launch(void* const* d_in, const int* in_sizes, int n_in,
                              void* d_out, int out_size, void* d_ws, size_t ws_size,
                              hipStream_t stream) {
  const float* X  = (const float*)d_in[0];
  const float* Wq = (const float*)d_in[1];
  const float* Wk = (const float*)d_in[2];
  const float* Wv = (const float*)d_in[3];

  // workspace layout (u16 elements)
  u16* Xb  = (u16*)d_ws;                // 8192*1024
  u16* Wqr = Xb + 8388608;              // 1M, row-major Wq*(1/32)
  u16* Wkr = Wqr + 1048576;             // 1M, row-major Wk
  u16* WG  = Wkr + 1048576;             // [Gt; Wvt] (2M) — contiguous B for T1V
  u16* T1  = WG + 2097152;              // 8192*1024
  u16* Vt  = T1 + 8388608;              // [b][1024][2048]
  u16* S   = Vt + 8388608;              // [b][2048][2048] -> holds P = exp(scores)
  float* sums = (float*)(S + 16777216); // [b][2048] row sums (32 KB)

  hipMemsetAsync(sums, 0, 4 * 2048 * sizeof(float), stream);

  // cast X, Wq (scaled), Wk row-major; transpose Wv (one dispatch)
  prep_kernel<<<5376, 256, 0, stream>>>(X, Wq, Wk, Wv, Xb, Wqr, Wkr, WG);

  // Gt = NT(Wkr, Wqr): Gt[d'][d] = M[d,d'] = Sum_e Wq[d,e]Wk[d',e]/32 — 2.1 GF
  gemm128<0><<<64, 256, 0, stream>>>(Wkr, Wqr, WG, nullptr);

  // [T1 | V] = NT(Xb, [Gt; Wvt]) — replaces Q, K and V projections
  gemm128<1><<<1024, 256, 0, stream>>>(Xb, WG, T1, Vt);

  // P = exp(T1 X^T) per batch (causal zeros; row sums via atomics)
  gemm_s<<<1088, 256, 0, stream>>>(T1, Xb, S, sums);

  // O = P V / rowsum
  gemm_pv<<<512, 512, 0, stream>>>(S, Vt, (float*)d_out, sums);
}